// Round 4
// baseline (2959.111 us; speedup 1.0000x reference)
//
#include <hip/hip_runtime.h>
#include <hip/hip_bf16.h>
#include <cmath>

#define NN 100000   // nodes
#define EE 600000   // edges
#define BB 512      // graphs
#define LL 10       // labels
// H=128; L1 256->512, L2 512->256, L3 256->128, L4 128->128, L5 128->10 (col-picked)

typedef __attribute__((ext_vector_type(8))) short  bf16x8;
typedef __attribute__((ext_vector_type(4))) float  f32x4;
typedef unsigned int uint;
typedef unsigned short ushort;

__device__ __forceinline__ float elu_f(float x){ return x > 0.f ? x : expm1f(x); }

__device__ __forceinline__ ushort bf16_rne(float f){
  uint u = __float_as_uint(f);
  return (ushort)((u + 0x7FFFu + ((u >> 16) & 1u)) >> 16);
}

__device__ __forceinline__ f32x4 MFMA(bf16x8 a, bf16x8 b, f32x4 c){
  return __builtin_amdgcn_mfma_f32_16x16x32_bf16(a, b, c, 0, 0, 0);
}

// Monotone float<->uint encoding for atomic max/min on floats
__device__ __forceinline__ unsigned enc_f(float f){
  unsigned u = __float_as_uint(f);
  return (u & 0x80000000u) ? ~u : (u | 0x80000000u);
}
__device__ __forceinline__ float dec_f(unsigned u){
  return (u & 0x80000000u) ? __uint_as_float(u ^ 0x80000000u) : __uint_as_float(~u);
}
#define ENC_NEG_INF 0x007FFFFFu

// ---------------------------------------------------------------------------
// kReps: repsF[n] = 512B row: [hi bf16 k=0..127][lo bf16 k=0..127].
// ---------------------------------------------------------------------------
__global__ __launch_bounds__(256) void kReps(const float* __restrict__ r0,
                                             const float* __restrict__ r1,
                                             ushort* __restrict__ repsF){
  int gid = blockIdx.x*256 + threadIdx.x;          // N*16 threads
  int n = gid >> 4, k8 = gid & 15;
  const float4* a = (const float4*)(r0 + (size_t)n*128 + k8*8);
  const float4* b = (const float4*)(r1 + (size_t)n*128 + k8*8);
  float4 x0 = a[0], x1 = a[1], y0 = b[0], y1 = b[1];
  float d[8] = {x0.x-y0.x, x0.y-y0.y, x0.z-y0.z, x0.w-y0.w,
                x1.x-y1.x, x1.y-y1.y, x1.z-y1.z, x1.w-y1.w};
  ushort hi[8], lo[8];
  #pragma unroll
  for (int j=0;j<8;++j){
    hi[j] = bf16_rne(d[j]);
    float fh = __uint_as_float(((uint)hi[j])<<16);
    lo[j] = bf16_rne(d[j] - fh);
  }
  ushort* dh = repsF + (size_t)n*256 + k8*8;
  ushort* dl = dh + 128;
  #pragma unroll
  for (int j=0;j<8;++j){ dh[j] = hi[j]; dl[j] = lo[j]; }
}

// ---------------------------------------------------------------------------
// kPrepW: weight [K][N] fp32 -> MFMA-fragment bf16 hi/lo:
//   dst[part][kt][nt][lane][j] with k = kt*32+(l>>4)*8+j, n = nt*16+(l&15).
// ---------------------------------------------------------------------------
__global__ __launch_bounds__(256) void kPrepW(const float* __restrict__ W, int N,
                                              int KT, int NT, ushort* __restrict__ dst){
  int gid = blockIdx.x*256 + threadIdx.x;
  int total = KT*NT*64;
  if (gid >= total) return;
  int l = gid & 63, tile = gid >> 6;
  int kt = tile / NT, nt = tile % NT;
  int kbase = kt*32 + (l>>4)*8;
  int n = nt*16 + (l&15);
  int partStride = KT*NT*512;
  int base = tile*512 + l*8;
  #pragma unroll
  for (int j=0;j<8;++j){
    float f = W[(size_t)(kbase+j)*N + n];
    ushort h = bf16_rne(f);
    float fh = __uint_as_float(((uint)h)<<16);
    dst[base + j] = h;
    dst[partStride + base + j] = bf16_rne(f - fh);
  }
}

// ---------------------------------------------------------------------------
// LDS transpose helpers (region = [part(2)][m(32)][col(64) pad 68] ushorts).
// xposeN: write NTILES n-tiles x 2 m-tiles of C-frags (bias, optional elu,
// hi/lo split) at the region base passed in (base may be col-offset by a
// multiple of 16 cols = 32 B, keeping uint alignment).
// readA: A-frag (8 consecutive cols at row m) as two b64 reads.
// ---------------------------------------------------------------------------
template<int NTILES>
__device__ __forceinline__ void xposeN(ushort* sT, const f32x4* Cg,
                                       const float* __restrict__ biasPtr,
                                       bool doElu, int l){
  const int quad = l >> 4, r16 = l & 15;
  uint* ldsu = (uint*)sT;
  #pragma unroll
  for (int i = 0; i < NTILES; ++i){
    float bv = biasPtr[i*16 + r16];
    #pragma unroll
    for (int mtl = 0; mtl < 2; ++mtl){
      f32x4 v = Cg[i*2 + mtl];
      ushort hi[4], lo[4];
      #pragma unroll
      for (int r = 0; r < 4; ++r){
        float f = v[r] + bv;
        if (doElu) f = elu_f(f);
        hi[r] = bf16_rne(f);
        float fh = __uint_as_float(((uint)hi[r]) << 16);
        lo[r] = bf16_rne(f - fh);
      }
      uint v01h = (uint)hi[0] | ((uint)hi[1]<<16);
      uint v23h = (uint)hi[2] | ((uint)hi[3]<<16);
      uint v01l = (uint)lo[0] | ((uint)lo[1]<<16);
      uint v23l = (uint)lo[2] | ((uint)lo[3]<<16);
      uint t01h = __shfl_xor(v01h,1), t23h = __shfl_xor(v23h,1);
      uint t01l = __shfl_xor(v01l,1), t23l = __shfl_xor(v23l,1);
      int c2 = (i*16 + (r16 & ~1)) >> 1;      // uint col index
      int m0 = mtl*16 + quad*4;
      if (!(l & 1)){
        ldsu[(m0+0)*34 + c2]        = (v01h & 0xFFFFu) | (t01h << 16);
        ldsu[(m0+1)*34 + c2]        = (v01h >> 16) | (t01h & 0xFFFF0000u);
        ldsu[1088 + (m0+0)*34 + c2] = (v01l & 0xFFFFu) | (t01l << 16);
        ldsu[1088 + (m0+1)*34 + c2] = (v01l >> 16) | (t01l & 0xFFFF0000u);
      } else {
        ldsu[(m0+2)*34 + c2]        = (t23h & 0xFFFFu) | (v23h << 16);
        ldsu[(m0+3)*34 + c2]        = (t23h >> 16) | (v23h & 0xFFFF0000u);
        ldsu[1088 + (m0+2)*34 + c2] = (t23l & 0xFFFFu) | (v23l << 16);
        ldsu[1088 + (m0+3)*34 + c2] = (t23l >> 16) | (v23l & 0xFFFF0000u);
      }
    }
  }
}

__device__ __forceinline__ bf16x8 readA(const ushort* region, int part, int m, int colBase){
  union { uint2 u[2]; bf16x8 v; } cvt;
  const ushort* p = region + part*2176 + m*68 + colBase;
  cvt.u[0] = *(const uint2*)p;
  cvt.u[1] = *(const uint2*)(p + 4);
  return cvt.v;
}

// ---------------------------------------------------------------------------
// R9 4-wave N-split helpers. All array indices compile-time (rule #20).
// produceSlice: wave w computes n-tile (s*4+w) of h1 (16 cols, K=256 full)
//               and xposes it into the slice buffer at col offset w*16.
// consumeSlice: all waves read the 64-col slice as MFMA-A (K-tiles 2s,2s+1)
//               and accumulate their N-quarter of h2 into C2q[8].
// ---------------------------------------------------------------------------
__device__ __forceinline__ void produceSlice(int s, int w, int l, int quad,
    const ushort* __restrict__ aS0, const ushort* __restrict__ aS1,
    const ushort* __restrict__ aD0, const ushort* __restrict__ aD1,
    const ushort* __restrict__ W1F, const float* __restrict__ b1,
    ushort* buf){
  f32x4 C1[2];
  C1[0] = (f32x4)0.f; C1[1] = (f32x4)0.f;
  #pragma unroll
  for (int hk = 0; hk < 8; ++hk){  // K=256: src k-tiles 0..3, dst 4..7
    const ushort* p0 = (hk < 4) ? aS0 : aD0;
    const ushort* p1 = (hk < 4) ? aS1 : aD1;
    const int ko = (hk & 3)*32 + quad*8;
    bf16x8 Ah0 = *(const bf16x8*)(p0 + ko);
    bf16x8 Al0 = *(const bf16x8*)(p0 + 128 + ko);
    bf16x8 Ah1 = *(const bf16x8*)(p1 + ko);
    bf16x8 Al1 = *(const bf16x8*)(p1 + 128 + ko);
    const bf16x8* WfH = (const bf16x8*)W1F + ((size_t)hk*32 + s*4 + w)*64 + l;
    const bf16x8* WfL = WfH + 8*32*64;
    bf16x8 Bh = WfH[0], Bl = WfL[0];
    C1[0] = MFMA(Ah0, Bh, C1[0]); C1[1] = MFMA(Ah1, Bh, C1[1]);
    C1[0] = MFMA(Ah0, Bl, C1[0]); C1[1] = MFMA(Ah1, Bl, C1[1]);
    C1[0] = MFMA(Al0, Bh, C1[0]); C1[1] = MFMA(Al1, Bh, C1[1]);
  }
  // n-tile -> slice buffer at col offset w*16 (16 ushorts, uint-aligned)
  xposeN<1>(buf + w*16, C1, b1 + s*64 + w*16, true, l);
}

__device__ __forceinline__ void consumeSlice(int s, int w, int l, int quad, int r16,
    const ushort* buf, const ushort* __restrict__ W2F, f32x4 (&C2q)[8]){
  #pragma unroll
  for (int j2 = 0; j2 < 2; ++j2){
    int colBase = j2*32 + quad*8;
    bf16x8 Ah[2], Al[2];
    #pragma unroll
    for (int mtl = 0; mtl < 2; ++mtl){
      int m = mtl*16 + r16;
      Ah[mtl] = readA(buf, 0, m, colBase);
      Al[mtl] = readA(buf, 1, m, colBase);
    }
    const int kt = s*2 + j2;                       // W2 k-tile (KT=16)
    const bf16x8* WfH = (const bf16x8*)W2F + ((size_t)kt*16 + w*4)*64 + l;
    const bf16x8* WfL = WfH + 16*16*64;
    #pragma unroll
    for (int j = 0; j < 4; ++j){
      bf16x8 Bh = WfH[j*64], Bl = WfL[j*64];
      f32x4 c0 = C2q[j*2], c1 = C2q[j*2+1];
      c0 = MFMA(Ah[0], Bh, c0); c1 = MFMA(Ah[1], Bh, c1);
      c0 = MFMA(Ah[0], Bl, c0); c1 = MFMA(Ah[1], Bl, c1);
      c0 = MFMA(Al[0], Bh, c0); c1 = MFMA(Al[1], Bh, c1);
      C2q[j*2] = c0; C2q[j*2+1] = c1;
    }
  }
}

// ---------------------------------------------------------------------------
// kMLP R9 (resubmit): 4-wave N-split workgroup, 32 edges per BLOCK.
// Motivation (R7/R8 counters): latency-bound at 17% MfmaUtil; occupancy
// hard-capped at 2 waves/SIMD by 256 regs/wave (C2=128 acc + 128 arch).
// Splitting every layer's N across 4 waves cuts accumulator state 4x:
//   L1/L2: C2q[8]=32 regs; slice (64 cols) produced 1 n-tile/wave into a
//          shared dbuf'd LDS region, consumed by all (produce-ahead, 1
//          barrier/slice). K-tile order 0..15 preserved -> identical math.
//   L3: h2 (4 regions, wave w xposes its 64 cols), C3q[4]. L4: h3 in 2
//       region-halves, C4q[4]. L5: partial dot + LDS cross-wave reduce.
// Regs ~110 peak -> __launch_bounds__(256,4): 16 waves/CU (2x R7).
// LDS: 4 regions (34.8 KB) + sTy + sRed ~ 35.5 KB -> 4 blocks/CU.
// ---------------------------------------------------------------------------
__global__ __launch_bounds__(256, 4) void kMLP(
    const ushort* __restrict__ repsF,
    const ushort* __restrict__ W1F, const ushort* __restrict__ W2F,
    const ushort* __restrict__ W3F, const ushort* __restrict__ W4F,
    const float* __restrict__ b1, const float* __restrict__ b2,
    const float* __restrict__ b3, const float* __restrict__ b4,
    const float* __restrict__ W5, const float* __restrict__ b5,
    const int* __restrict__ edge_index, const int* __restrict__ batch,
    const int* __restrict__ y,
    float* __restrict__ scores, int* __restrict__ ebatch)
{
  __shared__ __align__(16) ushort sR[4][4352];   // 4 regions x 8704 B
  __shared__ int sTy[32];
  __shared__ float sRed[4][32];

  const int tid = threadIdx.x;
  const int w = tid >> 6;                        // wave 0..3
  const int l = tid & 63;
  const int quad = l >> 4, r16 = l & 15;
  const int e0 = blockIdx.x * 32;

  if (tid < 32){
    int s = edge_index[e0 + tid];
    int eb = batch[s];
    ebatch[e0 + tid] = eb;
    sTy[tid] = y[eb];
  }

  // per-lane node row pointers (lane r16 owns edge m=r16 of each m-tile);
  // identical across waves -> barrier-locked phases give true L1 reuse.
  const int eA0 = e0 + r16, eA1 = e0 + 16 + r16;
  const ushort* aS0 = repsF + (size_t)edge_index[eA0]*256;
  const ushort* aS1 = repsF + (size_t)edge_index[eA1]*256;
  const ushort* aD0 = repsF + (size_t)edge_index[EE + eA0]*256;
  const ushort* aD1 = repsF + (size_t)edge_index[EE + eA1]*256;

  // ---- layers 1+2: h1 (N=512) in 8 slices of 64 cols; C2q accumulates ----
  f32x4 C2q[8];                    // 4 local n-tiles x 2 m-tiles (32 regs)
  #pragma unroll
  for (int i=0;i<8;++i) C2q[i] = (f32x4)0.f;

  produceSlice(0, w, l, quad, aS0, aS1, aD0, aD1, W1F, b1, sR[0]);
  __syncthreads();
  #pragma unroll 1
  for (int s = 0; s < 8; ++s){
    if (s < 7)
      produceSlice(s+1, w, l, quad, aS0, aS1, aD0, aD1, W1F, b1, sR[(s+1)&1]);
    consumeSlice(s, w, l, quad, r16, sR[s&1], W2F, C2q);
    __syncthreads();
  }

  // ---- h2 staging: wave w -> region w (cols w*64..w*64+63), elu+b2 ----
  xposeN<4>(sR[w], C2q, b2 + w*64, true, l);
  __syncthreads();

  // ---- layer 3: K=256 from h2 regions; wave w computes h3 cols w*32.. ----
  f32x4 C3q[4];
  #pragma unroll
  for (int i=0;i<4;++i) C3q[i] = (f32x4)0.f;
  #pragma unroll
  for (int kt = 0; kt < 8; ++kt){
    const ushort* reg = sR[kt >> 1];
    int colBase = (kt & 1)*32 + quad*8;
    bf16x8 Ah[2], Al[2];
    #pragma unroll
    for (int mtl = 0; mtl < 2; ++mtl){
      int m = mtl*16 + r16;
      Ah[mtl] = readA(reg, 0, m, colBase);
      Al[mtl] = readA(reg, 1, m, colBase);
    }
    const bf16x8* WfH = (const bf16x8*)W3F + ((size_t)kt*8 + w*2)*64 + l;
    const bf16x8* WfL = WfH + 8*8*64;
    #pragma unroll
    for (int j = 0; j < 2; ++j){
      bf16x8 Bh = WfH[j*64], Bl = WfL[j*64];
      f32x4 c0 = C3q[j*2], c1 = C3q[j*2+1];
      c0 = MFMA(Ah[0], Bh, c0); c1 = MFMA(Ah[1], Bh, c1);
      c0 = MFMA(Ah[0], Bl, c0); c1 = MFMA(Ah[1], Bl, c1);
      c0 = MFMA(Al[0], Bh, c0); c1 = MFMA(Al[1], Bh, c1);
      C3q[j*2] = c0; C3q[j*2+1] = c1;
    }
  }
  __syncthreads();   // all waves done reading h2 regions

  // ---- h3 staging (b3, NO elu): wave w -> region (w>>1), col off (w&1)*32 --
  xposeN<2>(sR[w>>1] + (w&1)*32, C3q, b3 + w*32, false, l);
  __syncthreads();

  // ---- layer 4: K=128 from h3 (regions 0-1); wave w -> h4 cols w*32.. ----
  f32x4 C4q[4];
  #pragma unroll
  for (int i=0;i<4;++i) C4q[i] = (f32x4)0.f;
  #pragma unroll
  for (int kt = 0; kt < 4; ++kt){
    const ushort* reg = sR[kt >> 1];
    int colBase = (kt & 1)*32 + quad*8;
    bf16x8 Ah[2], Al[2];
    #pragma unroll
    for (int mtl = 0; mtl < 2; ++mtl){
      int m = mtl*16 + r16;
      Ah[mtl] = readA(reg, 0, m, colBase);
      Al[mtl] = readA(reg, 1, m, colBase);
    }
    const bf16x8* WfH = (const bf16x8*)W4F + ((size_t)kt*8 + w*2)*64 + l;
    const bf16x8* WfL = WfH + 4*8*64;
    #pragma unroll
    for (int j = 0; j < 2; ++j){
      bf16x8 Bh = WfH[j*64], Bl = WfL[j*64];
      f32x4 c0 = C4q[j*2], c1 = C4q[j*2+1];
      c0 = MFMA(Ah[0], Bh, c0); c1 = MFMA(Ah[1], Bh, c1);
      c0 = MFMA(Ah[0], Bl, c0); c1 = MFMA(Ah[1], Bl, c1);
      c0 = MFMA(Al[0], Bh, c0); c1 = MFMA(Al[1], Bh, c1);
      C4q[j*2] = c0; C4q[j*2+1] = c1;
    }
  }

  // ---- layer 5: per-wave partial dot over its 32 h4 cols, LDS reduce ----
  int tvals[2][4];
  #pragma unroll
  for (int mtl=0;mtl<2;++mtl)
    #pragma unroll
    for (int r=0;r<4;++r) tvals[mtl][r] = sTy[mtl*16 + quad*4 + r];

  float p[2][4] = {{0.f,0.f,0.f,0.f},{0.f,0.f,0.f,0.f}};
  #pragma unroll
  for (int j = 0; j < 2; ++j){
    int n4 = (w*2 + j)*16 + r16;
    float bv = b4[n4];
    const float* w5r = W5 + n4*LL;
    #pragma unroll
    for (int mtl = 0; mtl < 2; ++mtl){
      f32x4 c = C4q[j*2+mtl];
      #pragma unroll
      for (int r=0;r<4;++r)
        p[mtl][r] += elu_f(c[r] + bv) * w5r[tvals[mtl][r]];
    }
  }
  #pragma unroll
  for (int d = 8; d >= 1; d >>= 1){
    #pragma unroll
    for (int mtl=0;mtl<2;++mtl)
      #pragma unroll
      for (int r=0;r<4;++r)
        p[mtl][r] += __shfl_down(p[mtl][r], d, 16);
  }
  if (r16 == 0){
    #pragma unroll
    for (int mtl=0;mtl<2;++mtl)
      #pragma unroll
      for (int r=0;r<4;++r){
        int m = mtl*16 + quad*4 + r;
        sRed[w][m] = p[mtl][r];
      }
  }
  __syncthreads();
  if (tid < 32){
    float s = sRed[0][tid] + sRed[1][tid] + sRed[2][tid] + sRed[3][tid];
    scores[e0 + tid] = s + b5[sTy[tid]];
  }
}

// ---------------------------------------------------------------------------
// Segment softmax / argmax passes (unchanged, verified)
// ---------------------------------------------------------------------------
__global__ void kInitSeg(unsigned* segmax, float* segsum, unsigned* gmax, int* gact){
  int b = blockIdx.x*blockDim.x + threadIdx.x;
  if (b < BB){ segmax[b] = ENC_NEG_INF; segsum[b] = 0.f; gmax[b] = ENC_NEG_INF; gact[b] = 0x7FFFFFFF; }
}

__global__ __launch_bounds__(256) void kSegMax(const float* __restrict__ scores,
                                               const int* __restrict__ eb,
                                               unsigned* __restrict__ segmax){
  __shared__ unsigned l[BB];
  for (int b = threadIdx.x; b < BB; b += 256) l[b] = 0u;
  __syncthreads();
  for (int e = blockIdx.x*256 + threadIdx.x; e < EE; e += gridDim.x*256)
    atomicMax(&l[eb[e]], enc_f(scores[e]));
  __syncthreads();
  for (int b = threadIdx.x; b < BB; b += 256)
    if (l[b]) atomicMax(&segmax[b], l[b]);
}

__global__ __launch_bounds__(256) void kExpSum(const float* __restrict__ scores,
                                               const int* __restrict__ eb,
                                               const unsigned* __restrict__ segmax,
                                               float* __restrict__ segsum,
                                               float* __restrict__ outprobs){
  __shared__ float l[BB];
  for (int b = threadIdx.x; b < BB; b += 256) l[b] = 0.f;
  __syncthreads();
  for (int e = blockIdx.x*256 + threadIdx.x; e < EE; e += gridDim.x*256){
    int b = eb[e];
    float ex = expf(scores[e] - dec_f(segmax[b]));
    outprobs[e] = ex;
    atomicAdd(&l[b], ex);
  }
  __syncthreads();
  for (int b = threadIdx.x; b < BB; b += 256)
    if (l[b] != 0.f) atomicAdd(&segsum[b], l[b]);
}

__global__ __launch_bounds__(256) void kProbMax(float* __restrict__ outprobs,
                                                const int* __restrict__ eb,
                                                const float* __restrict__ segsum,
                                                unsigned* __restrict__ gmax){
  __shared__ unsigned l[BB];
  for (int b = threadIdx.x; b < BB; b += 256) l[b] = 0u;
  __syncthreads();
  for (int e = blockIdx.x*256 + threadIdx.x; e < EE; e += gridDim.x*256){
    int b = eb[e];
    float p = outprobs[e] / segsum[b];
    outprobs[e] = p;
    atomicMax(&l[b], enc_f(p));
  }
  __syncthreads();
  for (int b = threadIdx.x; b < BB; b += 256)
    if (l[b]) atomicMax(&gmax[b], l[b]);
}

__global__ __launch_bounds__(256) void kArgMin(const float* __restrict__ outprobs,
                                               const int* __restrict__ eb,
                                               const unsigned* __restrict__ gmax,
                                               int* __restrict__ gact){
  __shared__ int l[BB];
  for (int b = threadIdx.x; b < BB; b += 256) l[b] = 0x7FFFFFFF;
  __syncthreads();
  for (int e = blockIdx.x*256 + threadIdx.x; e < EE; e += gridDim.x*256){
    int b = eb[e];
    if (enc_f(outprobs[e]) == gmax[b]) atomicMin(&l[b], e);
  }
  __syncthreads();
  for (int b = threadIdx.x; b < BB; b += 256)
    if (l[b] != 0x7FFFFFFF) atomicMin(&gact[b], l[b]);
}

__global__ void kFinal(const unsigned* __restrict__ gmax, const int* __restrict__ gact,
                       float* __restrict__ out){
  int b = threadIdx.x;
  if (b < BB){
    out[EE + b]      = dec_f(gmax[b]);
    out[EE + BB + b] = (float)gact[b];
  }
}

// ---------------------------------------------------------------------------
extern "C" void kernel_launch(void* const* d_in, const int* in_sizes, int n_in,
                              void* d_out, int out_size, void* d_ws, size_t ws_size,
                              hipStream_t stream){
  const float* r0 = (const float*)d_in[0];
  const float* r1 = (const float*)d_in[1];
  const float* W1 = (const float*)d_in[2];
  const float* b1 = (const float*)d_in[3];
  const float* W2 = (const float*)d_in[4];
  const float* b2 = (const float*)d_in[5];
  const float* W3 = (const float*)d_in[6];
  const float* b3 = (const float*)d_in[7];
  const float* W4 = (const float*)d_in[8];
  const float* b4 = (const float*)d_in[9];
  const float* W5 = (const float*)d_in[10];
  const float* b5 = (const float*)d_in[11];
  const int* edge_index = (const int*)d_in[12];
  const int* batch = (const int*)d_in[13];
  const int* y = (const int*)d_in[14];
  float* out = (float*)d_out;

  char* ws = (char*)d_ws;
  size_t off = 0;
  float*    scores = (float*)(ws + off);    off += (size_t)EE*4;
  int*      ebatch = (int*)(ws + off);      off += (size_t)EE*4;
  unsigned* segmax = (unsigned*)(ws + off); off += BB*4;
  float*    segsum = (float*)(ws + off);    off += BB*4;
  unsigned* gmax   = (unsigned*)(ws + off); off += BB*4;
  int*      gact   = (int*)(ws + off);      off += BB*4;
  off = (off + 511) & ~(size_t)511;
  ushort* repsF = (ushort*)(ws + off);      off += (size_t)NN*256*2;   // 51.2 MB
  ushort* W1F   = (ushort*)(ws + off);      off += (size_t)2*8*32*512*2;
  ushort* W2F   = (ushort*)(ws + off);      off += (size_t)2*16*16*512*2;
  ushort* W3F   = (ushort*)(ws + off);      off += (size_t)2*8*8*512*2;
  ushort* W4F   = (ushort*)(ws + off);      off += (size_t)2*4*8*512*2;

  kInitSeg<<<2, 256, 0, stream>>>(segmax, segsum, gmax, gact);
  kReps<<<(NN*16)/256, 256, 0, stream>>>(r0, r1, repsF);
  kPrepW<<<(8*32*64)/256, 256, 0, stream>>>(W1, 512, 8, 32, W1F);
  kPrepW<<<(16*16*64)/256, 256, 0, stream>>>(W2, 256, 16, 16, W2F);
  kPrepW<<<(8*8*64)/256, 256, 0, stream>>>(W3, 128, 8, 8, W3F);
  kPrepW<<<(4*8*64)/256, 256, 0, stream>>>(W4, 128, 4, 8, W4F);

  kMLP<<<EE/32, 256, 0, stream>>>(repsF, W1F, W2F, W3F, W4F,
                                  b1, b2, b3, b4, W5, b5,
                                  edge_index, batch, y, scores, ebatch);

  kSegMax <<<256, 256, 0, stream>>>(scores, ebatch, segmax);
  kExpSum <<<256, 256, 0, stream>>>(scores, ebatch, segmax, segsum, out);
  kProbMax<<<256, 256, 0, stream>>>(out, ebatch, segsum, gmax);
  kArgMin <<<256, 256, 0, stream>>>(out, ebatch, gmax, gact);
  kFinal  <<<1, 512, 0, stream>>>(gmax, gact, out);
}

// Round 5
// 2745.094 us; speedup vs baseline: 1.0780x; 1.0780x over previous
//
#include <hip/hip_runtime.h>
#include <hip/hip_bf16.h>
#include <cmath>

#define NN 100000   // nodes
#define EE 600000   // edges
#define BB 512      // graphs
#define LL 10       // labels
// H=128; L1 256->512, L2 512->256, L3 256->128, L4 128->128, L5 128->10 (col-picked)

typedef __attribute__((ext_vector_type(8))) short  bf16x8;
typedef __attribute__((ext_vector_type(4))) float  f32x4;
typedef unsigned int uint;
typedef unsigned short ushort;

__device__ __forceinline__ float elu_f(float x){ return x > 0.f ? x : expm1f(x); }

__device__ __forceinline__ ushort bf16_rne(float f){
  uint u = __float_as_uint(f);
  return (ushort)((u + 0x7FFFu + ((u >> 16) & 1u)) >> 16);
}

__device__ __forceinline__ f32x4 MFMA(bf16x8 a, bf16x8 b, f32x4 c){
  return __builtin_amdgcn_mfma_f32_16x16x32_bf16(a, b, c, 0, 0, 0);
}

// Monotone float<->uint encoding for atomic max/min on floats
__device__ __forceinline__ unsigned enc_f(float f){
  unsigned u = __float_as_uint(f);
  return (u & 0x80000000u) ? ~u : (u | 0x80000000u);
}
__device__ __forceinline__ float dec_f(unsigned u){
  return (u & 0x80000000u) ? __uint_as_float(u ^ 0x80000000u) : __uint_as_float(~u);
}
#define ENC_NEG_INF 0x007FFFFFu

// ---------------------------------------------------------------------------
// kReps: repsF[n] = 512B row: [hi bf16 k=0..127][lo bf16 k=0..127].
// ---------------------------------------------------------------------------
__global__ __launch_bounds__(256) void kReps(const float* __restrict__ r0,
                                             const float* __restrict__ r1,
                                             ushort* __restrict__ repsF){
  int gid = blockIdx.x*256 + threadIdx.x;          // N*16 threads
  int n = gid >> 4, k8 = gid & 15;
  const float4* a = (const float4*)(r0 + (size_t)n*128 + k8*8);
  const float4* b = (const float4*)(r1 + (size_t)n*128 + k8*8);
  float4 x0 = a[0], x1 = a[1], y0 = b[0], y1 = b[1];
  float d[8] = {x0.x-y0.x, x0.y-y0.y, x0.z-y0.z, x0.w-y0.w,
                x1.x-y1.x, x1.y-y1.y, x1.z-y1.z, x1.w-y1.w};
  ushort hi[8], lo[8];
  #pragma unroll
  for (int j=0;j<8;++j){
    hi[j] = bf16_rne(d[j]);
    float fh = __uint_as_float(((uint)hi[j])<<16);
    lo[j] = bf16_rne(d[j] - fh);
  }
  ushort* dh = repsF + (size_t)n*256 + k8*8;
  ushort* dl = dh + 128;
  #pragma unroll
  for (int j=0;j<8;++j){ dh[j] = hi[j]; dl[j] = lo[j]; }
}

// ---------------------------------------------------------------------------
// kPrepW: weight [K][N] fp32 -> MFMA-fragment bf16 hi/lo:
//   dst[part][kt][nt][lane][j] with k = kt*32+(l>>4)*8+j, n = nt*16+(l&15).
// ---------------------------------------------------------------------------
__global__ __launch_bounds__(256) void kPrepW(const float* __restrict__ W, int N,
                                              int KT, int NT, ushort* __restrict__ dst){
  int gid = blockIdx.x*256 + threadIdx.x;
  int total = KT*NT*64;
  if (gid >= total) return;
  int l = gid & 63, tile = gid >> 6;
  int kt = tile / NT, nt = tile % NT;
  int kbase = kt*32 + (l>>4)*8;
  int n = nt*16 + (l&15);
  int partStride = KT*NT*512;
  int base = tile*512 + l*8;
  #pragma unroll
  for (int j=0;j<8;++j){
    float f = W[(size_t)(kbase+j)*N + n];
    ushort h = bf16_rne(f);
    float fh = __uint_as_float(((uint)h)<<16);
    dst[base + j] = h;
    dst[partStride + base + j] = bf16_rne(f - fh);
  }
}

// ---------------------------------------------------------------------------
// LDS region (R10, M=64): [part(2)][m(64)][col(64) pad 68] ushorts.
// Region = 8704 ushorts = 17408 B. Part stride = 4352 ushorts = 2176 uints.
// xposeN<NT,MT>: write NT n-tiles x MT m-tiles of C-frags (bias, optional
// elu, hi/lo split). Pair-packed b32 writes as before.
// readA: A-frag (8 consecutive cols at row m) as two b64 reads.
// ---------------------------------------------------------------------------
template<int NTILES, int MTILES>
__device__ __forceinline__ void xposeN(ushort* sT, const f32x4* Cg,
                                       const float* __restrict__ biasPtr,
                                       bool doElu, int l){
  const int quad = l >> 4, r16 = l & 15;
  uint* ldsu = (uint*)sT;
  #pragma unroll
  for (int i = 0; i < NTILES; ++i){
    float bv = biasPtr[i*16 + r16];
    #pragma unroll
    for (int mtl = 0; mtl < MTILES; ++mtl){
      f32x4 v = Cg[i*MTILES + mtl];
      ushort hi[4], lo[4];
      #pragma unroll
      for (int r = 0; r < 4; ++r){
        float f = v[r] + bv;
        if (doElu) f = elu_f(f);
        hi[r] = bf16_rne(f);
        float fh = __uint_as_float(((uint)hi[r]) << 16);
        lo[r] = bf16_rne(f - fh);
      }
      uint v01h = (uint)hi[0] | ((uint)hi[1]<<16);
      uint v23h = (uint)hi[2] | ((uint)hi[3]<<16);
      uint v01l = (uint)lo[0] | ((uint)lo[1]<<16);
      uint v23l = (uint)lo[2] | ((uint)lo[3]<<16);
      uint t01h = __shfl_xor(v01h,1), t23h = __shfl_xor(v23h,1);
      uint t01l = __shfl_xor(v01l,1), t23l = __shfl_xor(v23l,1);
      int c2 = (i*16 + (r16 & ~1)) >> 1;      // uint col index
      int m0 = mtl*16 + quad*4;
      if (!(l & 1)){
        ldsu[(m0+0)*34 + c2]        = (v01h & 0xFFFFu) | (t01h << 16);
        ldsu[(m0+1)*34 + c2]        = (v01h >> 16) | (t01h & 0xFFFF0000u);
        ldsu[2176 + (m0+0)*34 + c2] = (v01l & 0xFFFFu) | (t01l << 16);
        ldsu[2176 + (m0+1)*34 + c2] = (v01l >> 16) | (t01l & 0xFFFF0000u);
      } else {
        ldsu[(m0+2)*34 + c2]        = (t23h & 0xFFFFu) | (v23h << 16);
        ldsu[(m0+3)*34 + c2]        = (t23h >> 16) | (v23h & 0xFFFF0000u);
        ldsu[2176 + (m0+2)*34 + c2] = (t23l & 0xFFFFu) | (v23l << 16);
        ldsu[2176 + (m0+3)*34 + c2] = (t23l >> 16) | (v23l & 0xFFFF0000u);
      }
    }
  }
}

__device__ __forceinline__ bf16x8 readA(const ushort* region, int part, int m, int colBase){
  union { uint2 u[2]; bf16x8 v; } cvt;
  const ushort* p = region + part*4352 + m*68 + colBase;
  cvt.u[0] = *(const uint2*)p;
  cvt.u[1] = *(const uint2*)(p + 4);
  return cvt.v;
}

// ---------------------------------------------------------------------------
// R10 helpers: 4-wave N-split, 64 edges (4 m-tiles) per block.
// produceSlice: wave w computes n-tile (s*4+w) of h1 (16 cols, full K=256)
//   for all 4 m-tiles and xposes into the slice buffer at col offset w*16.
//   A loads grouped in m-pairs to bound transient VGPRs.
// consumeSlice: all waves read the 64-col slice as MFMA-A (W2 k-tiles
//   2s,2s+1) and accumulate STRIDED n-tiles (j*4+w) of h2 into C2q[16].
//   (Strided ownership lets L3 process h2 in two 128-col K-halves with
//   every wave contributing 2 xpose tiles per half.)
// ---------------------------------------------------------------------------
__device__ __forceinline__ void produceSlice(int s, int w, int l, int quad,
    const ushort* const (&aS)[4], const ushort* const (&aD)[4],
    const ushort* __restrict__ W1F, const float* __restrict__ b1,
    ushort* buf){
  f32x4 C1[4];
  #pragma unroll
  for (int i=0;i<4;++i) C1[i] = (f32x4)0.f;
  #pragma unroll
  for (int hk = 0; hk < 8; ++hk){  // K=256: src k-tiles 0..3, dst 4..7
    const int ko = (hk & 3)*32 + quad*8;
    const bf16x8* WfH = (const bf16x8*)W1F + ((size_t)hk*32 + s*4 + w)*64 + l;
    const bf16x8* WfL = WfH + 8*32*64;
    bf16x8 Bh = WfH[0], Bl = WfL[0];
    #pragma unroll
    for (int g = 0; g < 2; ++g){         // m-tile pairs (VGPR bound)
      const ushort* p0 = (hk < 4) ? aS[g*2]   : aD[g*2];
      const ushort* p1 = (hk < 4) ? aS[g*2+1] : aD[g*2+1];
      bf16x8 Ah0 = *(const bf16x8*)(p0 + ko);
      bf16x8 Al0 = *(const bf16x8*)(p0 + 128 + ko);
      bf16x8 Ah1 = *(const bf16x8*)(p1 + ko);
      bf16x8 Al1 = *(const bf16x8*)(p1 + 128 + ko);
      f32x4 c0 = C1[g*2], c1 = C1[g*2+1];
      c0 = MFMA(Ah0, Bh, c0); c1 = MFMA(Ah1, Bh, c1);
      c0 = MFMA(Ah0, Bl, c0); c1 = MFMA(Ah1, Bl, c1);
      c0 = MFMA(Al0, Bh, c0); c1 = MFMA(Al1, Bh, c1);
      C1[g*2] = c0; C1[g*2+1] = c1;
    }
  }
  xposeN<1,4>(buf + w*16, C1, b1 + s*64 + w*16, true, l);
}

__device__ __forceinline__ void consumeSlice(int s, int w, int l, int quad, int r16,
    const ushort* buf, const ushort* __restrict__ W2F, f32x4 (&C2q)[16]){
  #pragma unroll
  for (int j2 = 0; j2 < 2; ++j2){
    int colBase = j2*32 + quad*8;
    bf16x8 Ah[4], Al[4];
    #pragma unroll
    for (int mt = 0; mt < 4; ++mt){
      int m = mt*16 + r16;
      Ah[mt] = readA(buf, 0, m, colBase);
      Al[mt] = readA(buf, 1, m, colBase);
    }
    const int kt = s*2 + j2;                       // W2 k-tile (KT=16)
    #pragma unroll
    for (int j = 0; j < 4; ++j){                   // strided n-tile j*4+w
      const bf16x8* WfH = (const bf16x8*)W2F + ((size_t)kt*16 + j*4 + w)*64 + l;
      const bf16x8* WfL = WfH + 16*16*64;
      bf16x8 Bh = WfH[0], Bl = WfL[0];
      #pragma unroll
      for (int mt = 0; mt < 4; ++mt){
        f32x4 c = C2q[j*4 + mt];
        c = MFMA(Ah[mt], Bh, c);
        c = MFMA(Ah[mt], Bl, c);
        c = MFMA(Al[mt], Bh, c);
        C2q[j*4 + mt] = c;
      }
    }
  }
}

// L3 K-half consume: h2 cols H*128..H*128+127 live in regions 0,1.
template<int H>
__device__ __forceinline__ void l3Consume(const ushort* sR0, const ushort* sR1,
    const ushort* __restrict__ W3F, int w, int l, int quad, int r16,
    f32x4 (&C3q)[8]){
  #pragma unroll
  for (int kt2 = 0; kt2 < 4; ++kt2){
    const ushort* reg = (kt2 & 2) ? sR1 : sR0;
    int colBase = (kt2 & 1)*32 + quad*8;
    bf16x8 Ah[4], Al[4];
    #pragma unroll
    for (int mt = 0; mt < 4; ++mt){
      int m = mt*16 + r16;
      Ah[mt] = readA(reg, 0, m, colBase);
      Al[mt] = readA(reg, 1, m, colBase);
    }
    const int kt = H*4 + kt2;                      // W3 k-tile (KT=8)
    #pragma unroll
    for (int j = 0; j < 2; ++j){
      const bf16x8* WfH = (const bf16x8*)W3F + ((size_t)kt*8 + w*2 + j)*64 + l;
      const bf16x8* WfL = WfH + 8*8*64;
      bf16x8 Bh = WfH[0], Bl = WfL[0];
      #pragma unroll
      for (int mt = 0; mt < 4; ++mt){
        f32x4 c = C3q[j*4 + mt];
        c = MFMA(Ah[mt], Bh, c);
        c = MFMA(Ah[mt], Bl, c);
        c = MFMA(Al[mt], Bh, c);
        C3q[j*4 + mt] = c;
      }
    }
  }
}

// ---------------------------------------------------------------------------
// kMLP R10: 64 edges/block (4 m-tiles), 4-wave N-split.
// Theory (R7-R9 counters): all prior variants stream 2.4 MB of weight
// fragments from L2 per 32 edges -> ~45 GB aggregate ~ 16 TB/s sustained
// L2 read BW; dur invariant under occupancy/scratch changes => L2-request
// bound. Doubling edges per weight pass halves per-edge weight traffic
// (MFMA:load ratio 1.5 -> 3). Occupancy drops to 2 waves/SIMD (R9 proved
// occupancy is not the lever). K-accumulation order per output element
// unchanged -> same numerics.
// LDS: 2 regions x 17408 B + sTy + sRed ~ 36 KB.
// ---------------------------------------------------------------------------
__global__ __launch_bounds__(256, 2) void kMLP(
    const ushort* __restrict__ repsF,
    const ushort* __restrict__ W1F, const ushort* __restrict__ W2F,
    const ushort* __restrict__ W3F, const ushort* __restrict__ W4F,
    const float* __restrict__ b1, const float* __restrict__ b2,
    const float* __restrict__ b3, const float* __restrict__ b4,
    const float* __restrict__ W5, const float* __restrict__ b5,
    const int* __restrict__ edge_index, const int* __restrict__ batch,
    const int* __restrict__ y,
    float* __restrict__ scores, int* __restrict__ ebatch)
{
  __shared__ __align__(16) ushort sR[2][8704];   // 2 regions x 17408 B
  __shared__ int sTy[64];
  __shared__ float sRed[4][64];

  const int tid = threadIdx.x;
  const int w = tid >> 6;                        // wave 0..3
  const int l = tid & 63;
  const int quad = l >> 4, r16 = l & 15;
  const int e0 = blockIdx.x * 64;

  if (tid < 64){
    int s = edge_index[e0 + tid];
    int eb = batch[s];
    ebatch[e0 + tid] = eb;
    sTy[tid] = y[eb];
  }

  // per-lane node row pointers: lane r16 owns edge m = mt*16+r16
  const ushort* aS[4]; const ushort* aD[4];
  #pragma unroll
  for (int mt = 0; mt < 4; ++mt){
    aS[mt] = repsF + (size_t)edge_index[e0 + mt*16 + r16]*256;
    aD[mt] = repsF + (size_t)edge_index[EE + e0 + mt*16 + r16]*256;
  }

  // ---- layers 1+2: h1 (N=512) in 8 slices of 64 cols; C2q accumulates ----
  f32x4 C2q[16];                   // 4 strided n-tiles x 4 m-tiles (64 regs)
  #pragma unroll
  for (int i=0;i<16;++i) C2q[i] = (f32x4)0.f;

  produceSlice(0, w, l, quad, aS, aD, W1F, b1, sR[0]);
  __syncthreads();
  #pragma unroll 1
  for (int s = 0; s < 8; ++s){
    if (s < 7)
      produceSlice(s+1, w, l, quad, aS, aD, W1F, b1, sR[(s+1)&1]);
    consumeSlice(s, w, l, quad, r16, sR[s&1], W2F, C2q);
    __syncthreads();
  }

  // ---- layer 3: h2 (K=256) in 2 K-halves of 128 cols ----
  // Half h: wave w xposes strided tiles T=8h+w (j=2h, region 0) and
  // T=8h+4+w (j=2h+1, region 1), both at col offset w*16.
  f32x4 C3q[8];
  #pragma unroll
  for (int i=0;i<8;++i) C3q[i] = (f32x4)0.f;

  xposeN<1,4>(sR[0] + w*16, &C2q[0], b2 + (w)*16,      true, l);
  xposeN<1,4>(sR[1] + w*16, &C2q[4], b2 + (4 + w)*16,  true, l);
  __syncthreads();
  l3Consume<0>(sR[0], sR[1], W3F, w, l, quad, r16, C3q);
  __syncthreads();
  xposeN<1,4>(sR[0] + w*16, &C2q[8],  b2 + (8 + w)*16,  true, l);
  xposeN<1,4>(sR[1] + w*16, &C2q[12], b2 + (12 + w)*16, true, l);
  __syncthreads();
  l3Consume<1>(sR[0], sR[1], W3F, w, l, quad, r16, C3q);
  __syncthreads();

  // ---- h3 staging (b3, NO elu): wave w -> region (w>>1), col (w&1)*32 ----
  xposeN<2,4>(sR[w>>1] + (w&1)*32, C3q, b3 + w*32, false, l);
  __syncthreads();

  // ---- layer 4: K=128 from h3 (regions 0-1); wave w -> h4 cols w*32.. ----
  f32x4 C4q[8];
  #pragma unroll
  for (int i=0;i<8;++i) C4q[i] = (f32x4)0.f;
  #pragma unroll
  for (int kt = 0; kt < 4; ++kt){
    const ushort* reg = sR[kt >> 1];
    int colBase = (kt & 1)*32 + quad*8;
    bf16x8 Ah[4], Al[4];
    #pragma unroll
    for (int mt = 0; mt < 4; ++mt){
      int m = mt*16 + r16;
      Ah[mt] = readA(reg, 0, m, colBase);
      Al[mt] = readA(reg, 1, m, colBase);
    }
    #pragma unroll
    for (int j = 0; j < 2; ++j){
      const bf16x8* WfH = (const bf16x8*)W4F + ((size_t)kt*8 + w*2 + j)*64 + l;
      const bf16x8* WfL = WfH + 4*8*64;
      bf16x8 Bh = WfH[0], Bl = WfL[0];
      #pragma unroll
      for (int mt = 0; mt < 4; ++mt){
        f32x4 c = C4q[j*4 + mt];
        c = MFMA(Ah[mt], Bh, c);
        c = MFMA(Ah[mt], Bl, c);
        c = MFMA(Al[mt], Bh, c);
        C4q[j*4 + mt] = c;
      }
    }
  }

  // ---- layer 5: per-wave partial dot over its 32 h4 cols, LDS reduce ----
  int tvals[4][4];
  #pragma unroll
  for (int mt=0;mt<4;++mt)
    #pragma unroll
    for (int r=0;r<4;++r) tvals[mt][r] = sTy[mt*16 + quad*4 + r];

  float p[4][4];
  #pragma unroll
  for (int mt=0;mt<4;++mt)
    #pragma unroll
    for (int r=0;r<4;++r) p[mt][r] = 0.f;

  #pragma unroll
  for (int j = 0; j < 2; ++j){
    int n4 = (w*2 + j)*16 + r16;
    float bv = b4[n4];
    const float* w5r = W5 + n4*LL;
    #pragma unroll
    for (int mt = 0; mt < 4; ++mt){
      f32x4 c = C4q[j*4 + mt];
      #pragma unroll
      for (int r=0;r<4;++r)
        p[mt][r] += elu_f(c[r] + bv) * w5r[tvals[mt][r]];
    }
  }
  #pragma unroll
  for (int d = 8; d >= 1; d >>= 1){
    #pragma unroll
    for (int mt=0;mt<4;++mt)
      #pragma unroll
      for (int r=0;r<4;++r)
        p[mt][r] += __shfl_down(p[mt][r], d, 16);
  }
  if (r16 == 0){
    #pragma unroll
    for (int mt=0;mt<4;++mt)
      #pragma unroll
      for (int r=0;r<4;++r){
        int m = mt*16 + quad*4 + r;
        sRed[w][m] = p[mt][r];
      }
  }
  __syncthreads();
  if (tid < 64){
    float s = sRed[0][tid] + sRed[1][tid] + sRed[2][tid] + sRed[3][tid];
    scores[e0 + tid] = s + b5[sTy[tid]];
  }
}

// ---------------------------------------------------------------------------
// Segment softmax / argmax passes (unchanged, verified)
// ---------------------------------------------------------------------------
__global__ void kInitSeg(unsigned* segmax, float* segsum, unsigned* gmax, int* gact){
  int b = blockIdx.x*blockDim.x + threadIdx.x;
  if (b < BB){ segmax[b] = ENC_NEG_INF; segsum[b] = 0.f; gmax[b] = ENC_NEG_INF; gact[b] = 0x7FFFFFFF; }
}

__global__ __launch_bounds__(256) void kSegMax(const float* __restrict__ scores,
                                               const int* __restrict__ eb,
                                               unsigned* __restrict__ segmax){
  __shared__ unsigned l[BB];
  for (int b = threadIdx.x; b < BB; b += 256) l[b] = 0u;
  __syncthreads();
  for (int e = blockIdx.x*256 + threadIdx.x; e < EE; e += gridDim.x*256)
    atomicMax(&l[eb[e]], enc_f(scores[e]));
  __syncthreads();
  for (int b = threadIdx.x; b < BB; b += 256)
    if (l[b]) atomicMax(&segmax[b], l[b]);
}

__global__ __launch_bounds__(256) void kExpSum(const float* __restrict__ scores,
                                               const int* __restrict__ eb,
                                               const unsigned* __restrict__ segmax,
                                               float* __restrict__ segsum,
                                               float* __restrict__ outprobs){
  __shared__ float l[BB];
  for (int b = threadIdx.x; b < BB; b += 256) l[b] = 0.f;
  __syncthreads();
  for (int e = blockIdx.x*256 + threadIdx.x; e < EE; e += gridDim.x*256){
    int b = eb[e];
    float ex = expf(scores[e] - dec_f(segmax[b]));
    outprobs[e] = ex;
    atomicAdd(&l[b], ex);
  }
  __syncthreads();
  for (int b = threadIdx.x; b < BB; b += 256)
    if (l[b] != 0.f) atomicAdd(&segsum[b], l[b]);
}

__global__ __launch_bounds__(256) void kProbMax(float* __restrict__ outprobs,
                                                const int* __restrict__ eb,
                                                const float* __restrict__ segsum,
                                                unsigned* __restrict__ gmax){
  __shared__ unsigned l[BB];
  for (int b = threadIdx.x; b < BB; b += 256) l[b] = 0u;
  __syncthreads();
  for (int e = blockIdx.x*256 + threadIdx.x; e < EE; e += gridDim.x*256){
    int b = eb[e];
    float p = outprobs[e] / segsum[b];
    outprobs[e] = p;
    atomicMax(&l[b], enc_f(p));
  }
  __syncthreads();
  for (int b = threadIdx.x; b < BB; b += 256)
    if (l[b]) atomicMax(&gmax[b], l[b]);
}

__global__ __launch_bounds__(256) void kArgMin(const float* __restrict__ outprobs,
                                               const int* __restrict__ eb,
                                               const unsigned* __restrict__ gmax,
                                               int* __restrict__ gact){
  __shared__ int l[BB];
  for (int b = threadIdx.x; b < BB; b += 256) l[b] = 0x7FFFFFFF;
  __syncthreads();
  for (int e = blockIdx.x*256 + threadIdx.x; e < EE; e += gridDim.x*256){
    int b = eb[e];
    if (enc_f(outprobs[e]) == gmax[b]) atomicMin(&l[b], e);
  }
  __syncthreads();
  for (int b = threadIdx.x; b < BB; b += 256)
    if (l[b] != 0x7FFFFFFF) atomicMin(&gact[b], l[b]);
}

__global__ void kFinal(const unsigned* __restrict__ gmax, const int* __restrict__ gact,
                       float* __restrict__ out){
  int b = threadIdx.x;
  if (b < BB){
    out[EE + b]      = dec_f(gmax[b]);
    out[EE + BB + b] = (float)gact[b];
  }
}

// ---------------------------------------------------------------------------
extern "C" void kernel_launch(void* const* d_in, const int* in_sizes, int n_in,
                              void* d_out, int out_size, void* d_ws, size_t ws_size,
                              hipStream_t stream){
  const float* r0 = (const float*)d_in[0];
  const float* r1 = (const float*)d_in[1];
  const float* W1 = (const float*)d_in[2];
  const float* b1 = (const float*)d_in[3];
  const float* W2 = (const float*)d_in[4];
  const float* b2 = (const float*)d_in[5];
  const float* W3 = (const float*)d_in[6];
  const float* b3 = (const float*)d_in[7];
  const float* W4 = (const float*)d_in[8];
  const float* b4 = (const float*)d_in[9];
  const float* W5 = (const float*)d_in[10];
  const float* b5 = (const float*)d_in[11];
  const int* edge_index = (const int*)d_in[12];
  const int* batch = (const int*)d_in[13];
  const int* y = (const int*)d_in[14];
  float* out = (float*)d_out;

  char* ws = (char*)d_ws;
  size_t off = 0;
  float*    scores = (float*)(ws + off);    off += (size_t)EE*4;
  int*      ebatch = (int*)(ws + off);      off += (size_t)EE*4;
  unsigned* segmax = (unsigned*)(ws + off); off += BB*4;
  float*    segsum = (float*)(ws + off);    off += BB*4;
  unsigned* gmax   = (unsigned*)(ws + off); off += BB*4;
  int*      gact   = (int*)(ws + off);      off += BB*4;
  off = (off + 511) & ~(size_t)511;
  ushort* repsF = (ushort*)(ws + off);      off += (size_t)NN*256*2;   // 51.2 MB
  ushort* W1F   = (ushort*)(ws + off);      off += (size_t)2*8*32*512*2;
  ushort* W2F   = (ushort*)(ws + off);      off += (size_t)2*16*16*512*2;
  ushort* W3F   = (ushort*)(ws + off);      off += (size_t)2*8*8*512*2;
  ushort* W4F   = (ushort*)(ws + off);      off += (size_t)2*4*8*512*2;

  kInitSeg<<<2, 256, 0, stream>>>(segmax, segsum, gmax, gact);
  kReps<<<(NN*16)/256, 256, 0, stream>>>(r0, r1, repsF);
  kPrepW<<<(8*32*64)/256, 256, 0, stream>>>(W1, 512, 8, 32, W1F);
  kPrepW<<<(16*16*64)/256, 256, 0, stream>>>(W2, 256, 16, 16, W2F);
  kPrepW<<<(8*8*64)/256, 256, 0, stream>>>(W3, 128, 8, 8, W3F);
  kPrepW<<<(4*8*64)/256, 256, 0, stream>>>(W4, 128, 4, 8, W4F);

  kMLP<<<EE/64, 256, 0, stream>>>(repsF, W1F, W2F, W3F, W4F,
                                  b1, b2, b3, b4, W5, b5,
                                  edge_index, batch, y, scores, ebatch);

  kSegMax <<<256, 256, 0, stream>>>(scores, ebatch, segmax);
  kExpSum <<<256, 256, 0, stream>>>(scores, ebatch, segmax, segsum, out);
  kProbMax<<<256, 256, 0, stream>>>(out, ebatch, segsum, gmax);
  kArgMin <<<256, 256, 0, stream>>>(out, ebatch, gmax, gact);
  kFinal  <<<1, 512, 0, stream>>>(gmax, gact, out);
}